// Round 1
// baseline (2574.048 us; speedup 1.0000x reference)
//
#include <hip/hip_runtime.h>
#include <hip/hip_bf16.h>

#define Bn 4096
#define Tn 8
#define Hn 512

__device__ __forceinline__ float sigm(float x) { return 0.5f * tanhf(0.5f * x) + 0.5f; }

// ---------------- setup kernels ----------------

// Wcat[j, 0:512] = Wih[j,:], Wcat[j, 512:1024] = Whh[j,:]; bcat[j] = bih[j]+bhh[j]
__global__ __launch_bounds__(256) void k_prep(const float* __restrict__ Wih,
                                              const float* __restrict__ Whh,
                                              const float* __restrict__ bih,
                                              const float* __restrict__ bhh,
                                              float* __restrict__ Wcat,
                                              float* __restrict__ bcat) {
    int tid = blockIdx.x * 256 + threadIdx.x;   // over 2048*1024
    int j = tid >> 10, k = tid & 1023;
    float v = (k < 512) ? Wih[j * 512 + k] : Whh[j * 512 + (k - 512)];
    Wcat[tid] = v;
    if (k == 0) bcat[j] = bih[j] + bhh[j];
}

// inp0 = sum_t enc[b,t,h]*cw[t] + cb ; zero h-part of X, zero C, zero mask
__global__ __launch_bounds__(256) void k_init(const float* __restrict__ enc,
                                              const float* __restrict__ cw,
                                              const float* __restrict__ cb,
                                              float* __restrict__ X,
                                              float* __restrict__ C,
                                              int* __restrict__ mask) {
    int tid = blockIdx.x * 256 + threadIdx.x;   // over B*H
    int b = tid >> 9, h = tid & 511;
    float s = cb[0];
    const float* e = enc + ((size_t)b << 12) + h;
#pragma unroll
    for (int t = 0; t < Tn; ++t) s = fmaf(e[t * Hn], cw[t], s);
    X[((size_t)b << 10) + h] = s;
    X[((size_t)b << 10) + 512 + h] = 0.0f;
    C[tid] = 0.0f;
    if (h == 0) mask[b] = 0;
}

// ---------------- fp32 GEMM: C[m,n] = A[m,:] . W[n,:] + bias[n] ----------------
// A: [M,K] row-major with leading dim lda.  W: [N,K] row-major (ld = K).
template <int TM, int TN>
__global__ __launch_bounds__(256) void gemm_nt(const float* __restrict__ A, int lda,
                                               const float* __restrict__ W,
                                               const float* __restrict__ bias,
                                               float* __restrict__ Cmat,
                                               int M, int N, int K) {
    constexpr int BM = TM * 16, BN = TN * 16, BK = 16;
    __shared__ float As[BK][BM];
    __shared__ float Bs[BK][BN];
    const int tid = threadIdx.x;
    const int tx = tid & 15;    // -> n
    const int ty = tid >> 4;    // -> m
    const int m0 = blockIdx.y * BM;
    const int n0 = blockIdx.x * BN;

    float acc[TM][TN] = {};

    for (int k0 = 0; k0 < K; k0 += BK) {
#pragma unroll
        for (int r = 0; r < TM / 4; ++r) {
            int qq = tid + r * 256;
            int m = qq >> 2, k4 = qq & 3;
            float4 av = *(const float4*)(A + (size_t)(m0 + m) * lda + k0 + k4 * 4);
            As[k4 * 4 + 0][m] = av.x; As[k4 * 4 + 1][m] = av.y;
            As[k4 * 4 + 2][m] = av.z; As[k4 * 4 + 3][m] = av.w;
        }
#pragma unroll
        for (int r = 0; r < TN / 4; ++r) {
            int qq = tid + r * 256;
            int n = qq >> 2, k4 = qq & 3;
            float4 bv = *(const float4*)(W + (size_t)(n0 + n) * K + k0 + k4 * 4);
            Bs[k4 * 4 + 0][n] = bv.x; Bs[k4 * 4 + 1][n] = bv.y;
            Bs[k4 * 4 + 2][n] = bv.z; Bs[k4 * 4 + 3][n] = bv.w;
        }
        __syncthreads();
#pragma unroll
        for (int k = 0; k < BK; ++k) {
            float a[TM], bb[TN];
#pragma unroll
            for (int i = 0; i < TM; i += 4)
                *(float4*)&a[i] = *(const float4*)&As[k][ty * TM + i];
#pragma unroll
            for (int j = 0; j < TN; j += 4)
                *(float4*)&bb[j] = *(const float4*)&Bs[k][tx * TN + j];
#pragma unroll
            for (int i = 0; i < TM; ++i)
#pragma unroll
                for (int j = 0; j < TN; ++j)
                    acc[i][j] = fmaf(a[i], bb[j], acc[i][j]);
        }
        __syncthreads();
    }

#pragma unroll
    for (int i = 0; i < TM; ++i) {
        size_t base = (size_t)(m0 + ty * TM + i) * N + (n0 + tx * TN);
#pragma unroll
        for (int j = 0; j < TN; j += 4) {
            float4 v;
            v.x = acc[i][j + 0] + bias[n0 + tx * TN + j + 0];
            v.y = acc[i][j + 1] + bias[n0 + tx * TN + j + 1];
            v.z = acc[i][j + 2] + bias[n0 + tx * TN + j + 2];
            v.w = acc[i][j + 3] + bias[n0 + tx * TN + j + 3];
            *(float4*)(Cmat + base + j) = v;
        }
    }
}

// ---------------- LSTM cell ----------------
__global__ __launch_bounds__(256) void k_cell(const float* __restrict__ gates,
                                              float* __restrict__ X,
                                              float* __restrict__ C) {
    int tid = blockIdx.x * 256 + threadIdx.x;   // over B*H
    int b = tid >> 9, h = tid & 511;
    const float* g = gates + ((size_t)b << 11);
    float gi = g[h], gf = g[h + 512], gg = g[h + 1024], go = g[h + 1536];
    float c = sigm(gf) * C[tid] + sigm(gi) * tanhf(gg);
    float hn = sigm(go) * tanhf(c);
    C[tid] = c;
    X[((size_t)b << 10) + 512 + h] = hn;
}

// ---------------- attention + argmax + gather ----------------
__global__ __launch_bounds__(256) void k_attn(const float* __restrict__ W1E,
                                              const float* __restrict__ W2h,
                                              const float* __restrict__ vw,
                                              const float* __restrict__ vbp,
                                              const float* __restrict__ inps,
                                              float* __restrict__ X,
                                              int* __restrict__ mask,
                                              float* __restrict__ probs,
                                              float* __restrict__ ptrs,
                                              int step) {
    const int b = blockIdx.x;
    const int tid = threadIdx.x;
    __shared__ float sU[Tn];
    __shared__ float red[4];
    __shared__ int sptr;

    float w2a = W2h[(size_t)b * Hn + tid];
    float w2b = W2h[(size_t)b * Hn + 256 + tid];
    float va = vw[tid], vb2 = vw[256 + tid];

    for (int t = 0; t < Tn; ++t) {
        const float* w1 = W1E + ((size_t)b << 12) + t * Hn;
        float p = va * tanhf(w1[tid] + w2a) + vb2 * tanhf(w1[256 + tid] + w2b);
#pragma unroll
        for (int off = 32; off; off >>= 1) p += __shfl_down(p, off, 64);
        if ((tid & 63) == 0) red[tid >> 6] = p;
        __syncthreads();
        if (tid == 0) sU[t] = red[0] + red[1] + red[2] + red[3] + vbp[0];
        __syncthreads();
    }

    if (tid == 0) {
        int mk = mask[b];
        float best = -1e30f;
        int ptr = 0;
#pragma unroll
        for (int t = 0; t < Tn; ++t) {
            probs[(size_t)b * 64 + step * 8 + t] = sU[t];
            if (!((mk >> t) & 1) && sU[t] > best) { best = sU[t]; ptr = t; }
        }
        mask[b] = mk | (1 << ptr);
        ptrs[(size_t)b * 8 + step] = (float)ptr;
        sptr = ptr;
    }
    __syncthreads();
    const float* src = inps + ((size_t)b << 12) + (size_t)sptr * Hn;
    X[((size_t)b << 10) + tid] = src[tid];
    X[((size_t)b << 10) + 256 + tid] = src[256 + tid];
}

// ---------------- launch ----------------
extern "C" void kernel_launch(void* const* d_in, const int* in_sizes, int n_in,
                              void* d_out, int out_size, void* d_ws, size_t ws_size,
                              hipStream_t stream) {
    const float* inps  = (const float*)d_in[0];
    const float* enc   = (const float*)d_in[1];
    const float* convw = (const float*)d_in[2];
    const float* convb = (const float*)d_in[3];
    const float* Wih   = (const float*)d_in[4];
    const float* Whh   = (const float*)d_in[5];
    const float* bih   = (const float*)d_in[6];
    const float* bhh   = (const float*)d_in[7];
    const float* W1    = (const float*)d_in[8];
    const float* b1    = (const float*)d_in[9];
    const float* W2    = (const float*)d_in[10];
    const float* b2    = (const float*)d_in[11];
    const float* vw    = (const float*)d_in[12];
    const float* vb    = (const float*)d_in[13];

    float* out   = (float*)d_out;
    float* probs = out;                       // [B, 8, 8]
    float* ptrs  = out + (size_t)Bn * 64;     // [B, 8] as float

    float* ws    = (float*)d_ws;
    float* W1E   = ws;                        // 16,777,216
    float* X     = W1E + (size_t)Bn * Tn * Hn;        // [B,1024]: inp | h
    float* C     = X + (size_t)Bn * 1024;             // [B,512]
    float* gates = C + (size_t)Bn * 512;              // [B,2048]
    float* W2h   = gates + (size_t)Bn * 2048;         // [B,512]
    float* Wcat  = W2h + (size_t)Bn * 512;            // [2048,1024]
    float* bcat  = Wcat + (size_t)2048 * 1024;        // [2048]
    int*   mask  = (int*)(bcat + 2048);               // [B]

    // setup
    k_prep<<<(2048 * 1024) / 256, 256, 0, stream>>>(Wih, Whh, bih, bhh, Wcat, bcat);
    k_init<<<(Bn * Hn) / 256, 256, 0, stream>>>(enc, convw, convb, X, C, mask);

    // W1E = enc([B*T,H]) @ W1^T + b1  -> [B*T, H]
    gemm_nt<8, 8><<<dim3(Hn / 128, (Bn * Tn) / 128), 256, 0, stream>>>(
        enc, Hn, W1, b1, W1E, Bn * Tn, Hn, Hn);

    for (int step = 0; step < Tn; ++step) {
        // gates = [inp|h] @ [Wih|Whh]^T + (bih+bhh)   [4096,2048], K=1024
        gemm_nt<8, 8><<<dim3(2048 / 128, Bn / 128), 256, 0, stream>>>(
            X, 1024, Wcat, bcat, gates, Bn, 2048, 1024);
        // LSTM cell -> h (into X[:,512:]), c
        k_cell<<<(Bn * Hn) / 256, 256, 0, stream>>>(gates, X, C);
        // W2h = h @ W2^T + b2   [4096,512], K=512
        gemm_nt<4, 4><<<dim3(Hn / 64, Bn / 64), 256, 0, stream>>>(
            X + 512, 1024, W2, b2, W2h, Bn, Hn, Hn);
        // attention scores, argmax, mask update, gather next input
        k_attn<<<Bn, 256, 0, stream>>>(W1E, W2h, vw, vb, inps, X, mask, probs, ptrs, step);
    }
}

// Round 3
// 1424.534 us; speedup vs baseline: 1.8069x; 1.8069x over previous
//
#include <hip/hip_runtime.h>
#include <hip/hip_bf16.h>

#define Bn 4096
#define Tn 8
#define Hn 512

typedef __attribute__((ext_vector_type(8))) short short8v;
typedef __attribute__((ext_vector_type(8))) _Float16 half8v;
typedef __attribute__((ext_vector_type(4))) float f32x4;

__device__ __forceinline__ float sigm(float x) { return 0.5f * tanhf(0.5f * x) + 0.5f; }

__device__ __forceinline__ short f2h(float x) {
    _Float16 h = (_Float16)x;               // RTN
    return *reinterpret_cast<short*>(&h);
}
__device__ __forceinline__ float h2f(short s) {
    _Float16 h = *reinterpret_cast<_Float16*>(&s);
    return (float)h;
}
// x ≈ hi + lo*2^-12 ; lo stored pre-scaled by 2^12 so it stays fp16-normal
__device__ __forceinline__ void split2(float x, short& hi, short& lo) {
    hi = f2h(x);
    lo = f2h((x - h2f(hi)) * 4096.0f);
}

#define GLOAD16(g, l) __builtin_amdgcn_global_load_lds( \
    (const __attribute__((address_space(1))) unsigned int*)(g), \
    (__attribute__((address_space(3))) unsigned int*)(l), 16, 0, 0)

// ---------------- setup kernels ----------------

__global__ __launch_bounds__(256) void k_prep(const float* __restrict__ Wih,
                                              const float* __restrict__ Whh,
                                              const float* __restrict__ bih,
                                              const float* __restrict__ bhh,
                                              short* __restrict__ WcatHi,
                                              short* __restrict__ WcatLo,
                                              float* __restrict__ bcat) {
    int tid = blockIdx.x * 256 + threadIdx.x;   // over 2048*1024
    int j = tid >> 10, k = tid & 1023;
    float v = (k < 512) ? Wih[j * 512 + k] : Whh[j * 512 + (k - 512)];
    short hi, lo; split2(v, hi, lo);
    WcatHi[tid] = hi; WcatLo[tid] = lo;
    if (k == 0) bcat[j] = bih[j] + bhh[j];
}

__global__ __launch_bounds__(256) void k_split(const float* __restrict__ x,
                                               short* __restrict__ hi,
                                               short* __restrict__ lo, int n) {
    int i = blockIdx.x * 256 + threadIdx.x;
    if (i < n) { short h, l; split2(x[i], h, l); hi[i] = h; lo[i] = l; }
}

// inp0 = sum_t enc[b,t,h]*cw[t] + cb ; zero h-part of X, zero C, zero mask
__global__ __launch_bounds__(256) void k_init(const float* __restrict__ enc,
                                              const float* __restrict__ cw,
                                              const float* __restrict__ cb,
                                              short* __restrict__ Xhi,
                                              short* __restrict__ Xlo,
                                              float* __restrict__ C,
                                              int* __restrict__ mask) {
    int tid = blockIdx.x * 256 + threadIdx.x;   // over B*H
    int b = tid >> 9, h = tid & 511;
    float s = cb[0];
    const float* e = enc + ((size_t)b << 12) + h;
#pragma unroll
    for (int t = 0; t < Tn; ++t) s = fmaf(e[t * Hn], cw[t], s);
    short hi, lo; split2(s, hi, lo);
    size_t xb = ((size_t)b << 10) + h;
    Xhi[xb] = hi; Xlo[xb] = lo;
    Xhi[xb + 512] = 0; Xlo[xb + 512] = 0;
    C[tid] = 0.0f;
    if (h == 0) mask[b] = 0;
}

// ---------------- split-fp16 MFMA GEMM ----------------
// C[m,n] = sum_k (Ahi + Alo*2^-12)[m,k] * (Whi + Wlo*2^-12)[n,k] + bias[n]
// products: hh (acc) ; hi*lo + lo*hi (acc2, folded * 2^-12 at epilogue)
// A: [M,K] fp16 pair, leading dim lda. W: [N,K] fp16 pair (ld=K). 128x128 tile, BK=32.
__global__ __launch_bounds__(256) void gemm_mfma(
    const short* __restrict__ Ahi, const short* __restrict__ Alo, int lda,
    const short* __restrict__ Whi, const short* __restrict__ Wlo,
    const float* __restrict__ bias, float* __restrict__ Cmat,
    int N, int K) {
    __shared__ short sm[4][128 * 32];
    const int tid = threadIdx.x;
    const int lane = tid & 63;
    const int wv = tid >> 6;
    const int wm = wv >> 1, wn = wv & 1;
    const int lm = lane & 15, lk = lane >> 4;
    const int m0 = blockIdx.y * 128, n0 = blockIdx.x * 128;

    const int sq = lane & 3;               // 16B chunk within a 64B row
    const int srow = wv * 16 + (lane >> 2);

    f32x4 acc[4][4] = {};
    f32x4 acc2[4][4] = {};

    for (int k0 = 0; k0 < K; k0 += 32) {
        // stage Ahi/Alo/Whi/Wlo tiles (pre-swizzled source, linear LDS dest)
#pragma unroll
        for (int half = 0; half < 2; ++half) {
            int r = half * 64 + srow;
            int qg = sq ^ ((r >> 1) & 3);
            size_t aoff = (size_t)(m0 + r) * lda + k0 + qg * 8;
            size_t boff = (size_t)(n0 + r) * K + k0 + qg * 8;
            int lbase = half * 2048 + wv * 512;   // shorts
            GLOAD16(Ahi + aoff, &sm[0][lbase]);
            GLOAD16(Alo + aoff, &sm[1][lbase]);
            GLOAD16(Whi + boff, &sm[2][lbase]);
            GLOAD16(Wlo + boff, &sm[3][lbase]);
        }
        __syncthreads();

        half8v ahi[4], alo[4], bhi[4], blo[4];
#pragma unroll
        for (int i = 0; i < 4; ++i) {
            int ra = wm * 64 + i * 16 + lm;
            int offa = ra * 32 + (lk ^ ((ra >> 1) & 3)) * 8;
            ahi[i] = *(const half8v*)&sm[0][offa];
            alo[i] = *(const half8v*)&sm[1][offa];
            int rb = wn * 64 + i * 16 + lm;
            int offb = rb * 32 + (lk ^ ((rb >> 1) & 3)) * 8;
            bhi[i] = *(const half8v*)&sm[2][offb];
            blo[i] = *(const half8v*)&sm[3][offb];
        }
#pragma unroll
        for (int i = 0; i < 4; ++i)
#pragma unroll
            for (int j = 0; j < 4; ++j) {
                acc[i][j]  = __builtin_amdgcn_mfma_f32_16x16x32_f16(ahi[i], bhi[j], acc[i][j], 0, 0, 0);
                acc2[i][j] = __builtin_amdgcn_mfma_f32_16x16x32_f16(ahi[i], blo[j], acc2[i][j], 0, 0, 0);
                acc2[i][j] = __builtin_amdgcn_mfma_f32_16x16x32_f16(alo[i], bhi[j], acc2[i][j], 0, 0, 0);
            }
        __syncthreads();
    }

    const float ls = 1.0f / 4096.0f;
#pragma unroll
    for (int j = 0; j < 4; ++j) {
        int col = n0 + wn * 64 + j * 16 + lm;
        float bb = bias[col];
#pragma unroll
        for (int i = 0; i < 4; ++i) {
            int row = m0 + wm * 64 + i * 16 + lk * 4;
#pragma unroll
            for (int r = 0; r < 4; ++r)
                Cmat[(size_t)(row + r) * N + col] = acc[i][j][r] + ls * acc2[i][j][r] + bb;
        }
    }
}

// ---------------- LSTM cell ----------------
__global__ __launch_bounds__(256) void k_cell(const float* __restrict__ gates,
                                              short* __restrict__ Xhi,
                                              short* __restrict__ Xlo,
                                              float* __restrict__ C) {
    int tid = blockIdx.x * 256 + threadIdx.x;   // over B*H
    int b = tid >> 9, h = tid & 511;
    const float* g = gates + ((size_t)b << 11);
    float gi = g[h], gf = g[h + 512], gg = g[h + 1024], go = g[h + 1536];
    float c = sigm(gf) * C[tid] + sigm(gi) * tanhf(gg);
    float hn = sigm(go) * tanhf(c);
    C[tid] = c;
    short hi, lo; split2(hn, hi, lo);
    size_t xb = ((size_t)b << 10) + 512 + h;
    Xhi[xb] = hi; Xlo[xb] = lo;
}

// ---------------- attention + argmax + gather ----------------
__global__ __launch_bounds__(256) void k_attn(const float* __restrict__ W1E,
                                              const float* __restrict__ W2h,
                                              const float* __restrict__ vw,
                                              const float* __restrict__ vbp,
                                              const float* __restrict__ inps,
                                              short* __restrict__ Xhi,
                                              short* __restrict__ Xlo,
                                              int* __restrict__ mask,
                                              float* __restrict__ probs,
                                              float* __restrict__ ptrs,
                                              int step) {
    const int b = blockIdx.x;
    const int tid = threadIdx.x;
    __shared__ float sU[Tn];
    __shared__ float red[4];
    __shared__ int sptr;

    float w2a = W2h[(size_t)b * Hn + tid];
    float w2b = W2h[(size_t)b * Hn + 256 + tid];
    float va = vw[tid], vb2 = vw[256 + tid];

    for (int t = 0; t < Tn; ++t) {
        const float* w1 = W1E + ((size_t)b << 12) + t * Hn;
        float p = va * tanhf(w1[tid] + w2a) + vb2 * tanhf(w1[256 + tid] + w2b);
#pragma unroll
        for (int off = 32; off; off >>= 1) p += __shfl_down(p, off, 64);
        if ((tid & 63) == 0) red[tid >> 6] = p;
        __syncthreads();
        if (tid == 0) sU[t] = red[0] + red[1] + red[2] + red[3] + vbp[0];
        __syncthreads();
    }

    if (tid == 0) {
        int mk = mask[b];
        float best = -1e30f;
        int ptr = 0;
#pragma unroll
        for (int t = 0; t < Tn; ++t) {
            probs[(size_t)b * 64 + step * 8 + t] = sU[t];
            if (!((mk >> t) & 1) && sU[t] > best) { best = sU[t]; ptr = t; }
        }
        mask[b] = mk | (1 << ptr);
        ptrs[(size_t)b * 8 + step] = (float)ptr;
        sptr = ptr;
    }
    __syncthreads();
    const float* src = inps + ((size_t)b << 12) + (size_t)sptr * Hn;
    size_t xb = ((size_t)b << 10);
#pragma unroll
    for (int q = 0; q < 2; ++q) {
        int h = tid + q * 256;
        short hi, lo; split2(src[h], hi, lo);
        Xhi[xb + h] = hi; Xlo[xb + h] = lo;
    }
}

// ---------------- launch ----------------
extern "C" void kernel_launch(void* const* d_in, const int* in_sizes, int n_in,
                              void* d_out, int out_size, void* d_ws, size_t ws_size,
                              hipStream_t stream) {
    const float* inps  = (const float*)d_in[0];
    const float* enc   = (const float*)d_in[1];
    const float* convw = (const float*)d_in[2];
    const float* convb = (const float*)d_in[3];
    const float* Wih   = (const float*)d_in[4];
    const float* Whh   = (const float*)d_in[5];
    const float* bih   = (const float*)d_in[6];
    const float* bhh   = (const float*)d_in[7];
    const float* W1    = (const float*)d_in[8];
    const float* b1    = (const float*)d_in[9];
    const float* W2    = (const float*)d_in[10];
    const float* b2    = (const float*)d_in[11];
    const float* vw    = (const float*)d_in[12];
    const float* vb    = (const float*)d_in[13];

    float* out   = (float*)d_out;
    float* probs = out;                       // [B, 8, 8]
    float* ptrs  = out + (size_t)Bn * 64;     // [B, 8] as float

    char* wsb = (char*)d_ws;
    float* W1E    = (float*)wsb;                          // [0,64MB)   fp32 [B*T,512]
    short* encHi  = (short*)(wsb + (64ull << 20));        // [64,96MB)  dead after W1E gemm
    short* encLo  = (short*)(wsb + (96ull << 20));        // [96,128MB)
    // reuse of [64,128MB) after W1E gemm:
    float* gates  = (float*)(wsb + (64ull << 20));        // 32MB fp32 [B,2048]
    float* W2h    = (float*)(wsb + (96ull << 20));        // 8MB  fp32 [B,512]
    float* C      = (float*)(wsb + (104ull << 20));       // 8MB  fp32 [B,512]
    short* Xhi    = (short*)(wsb + (112ull << 20));       // 8MB  fp16 [B,1024]
    short* Xlo    = (short*)(wsb + (120ull << 20));       // 8MB
    short* WcatHi = (short*)(wsb + (128ull << 20));       // 4MB  [2048,1024]
    short* WcatLo = (short*)(wsb + (132ull << 20));       // 4MB
    short* W1hi   = (short*)(wsb + (136ull << 20));                   // 512KB
    short* W1lo   = (short*)(wsb + (136ull << 20) + (512u << 10));
    short* W2hi   = (short*)(wsb + (137ull << 20));
    short* W2lo   = (short*)(wsb + (137ull << 20) + (512u << 10));
    float* bcat   = (float*)(wsb + (138ull << 20));       // 8KB
    int*   mask   = (int*)(wsb + (138ull << 20) + (16u << 10));

    // setup + one-time splits
    k_prep<<<(2048 * 1024) / 256, 256, 0, stream>>>(Wih, Whh, bih, bhh, WcatHi, WcatLo, bcat);
    k_split<<<(Bn * Tn * Hn) / 256, 256, 0, stream>>>(enc, encHi, encLo, Bn * Tn * Hn);
    k_split<<<(Hn * Hn) / 256, 256, 0, stream>>>(W1, W1hi, W1lo, Hn * Hn);
    k_split<<<(Hn * Hn) / 256, 256, 0, stream>>>(W2, W2hi, W2lo, Hn * Hn);

    // W1E = enc @ W1^T + b1   [B*T, 512], K=512
    gemm_mfma<<<dim3(Hn / 128, (Bn * Tn) / 128), 256, 0, stream>>>(
        encHi, encLo, Hn, W1hi, W1lo, b1, W1E, Hn, Hn);

    k_init<<<(Bn * Hn) / 256, 256, 0, stream>>>(enc, convw, convb, Xhi, Xlo, C, mask);

    for (int step = 0; step < Tn; ++step) {
        // gates = [inp|h] @ [Wih|Whh]^T + (bih+bhh)   [4096,2048], K=1024
        gemm_mfma<<<dim3(2048 / 128, Bn / 128), 256, 0, stream>>>(
            Xhi, Xlo, 1024, WcatHi, WcatLo, bcat, gates, 2048, 1024);
        // LSTM cell -> h (into X[:,512:] as hi/lo), c
        k_cell<<<(Bn * Hn) / 256, 256, 0, stream>>>(gates, Xhi, Xlo, C);
        // W2h = h @ W2^T + b2   [4096,512], K=512
        gemm_mfma<<<dim3(Hn / 128, Bn / 128), 256, 0, stream>>>(
            Xhi + 512, Xlo + 512, 1024, W2hi, W2lo, b2, W2h, Hn, Hn);
        // attention scores, argmax, mask update, gather next input
        k_attn<<<Bn, 256, 0, stream>>>(W1E, W2h, vw, vb, inps, Xhi, Xlo, mask, probs, ptrs, step);
    }
}